// Round 14
// baseline (325.690 us; speedup 1.0000x reference)
//
#include <hip/hip_runtime.h>
#include <hip/hip_bf16.h>
#include <math.h>

#define T_DIM 64
#define B_DIM 32
#define S_TOT 16384
#define BA 256
#define FN_SB 16

#define ACT_OFF 0
#define LP_OFF 32768
#define ENT_OFF 49152

typedef __attribute__((ext_vector_type(8))) short short8;
typedef __attribute__((ext_vector_type(4))) float f32x4;
typedef unsigned int uint32;

__device__ __forceinline__ float sigf(float x) { return 1.0f / (1.0f + expf(-x)); }
__device__ __forceinline__ float bf2f(unsigned short u) {
    union { unsigned int i; float f; } a; a.i = ((unsigned int)u) << 16; return a.f;
}
__device__ __forceinline__ uint32 pkbf(float a, float b) {
    __hip_bfloat16 ha = __float2bfloat16(a), hb = __float2bfloat16(b);
    return (uint32)(*(unsigned short*)&ha) | ((uint32)(*(unsigned short*)&hb) << 16);
}
__device__ __forceinline__ short f2bs(float v) {
    __hip_bfloat16 h = __float2bfloat16(v); return *(short*)&h;
}
__device__ __forceinline__ int pswz(int row) { return (((row & 3) ^ ((row >> 2) & 3)) << 4); }

// ---------------------------------------------------------------------------
// k_cvt2: pack all MFMA weights to bf16 (unchanged).
// ---------------------------------------------------------------------------
__global__ __launch_bounds__(256) void k_cvt2(
    const float* __restrict__ inp_w, const float* __restrict__ outp_w,
    const float* __restrict__ outp_b, const float* __restrict__ sa_w,
    const float* __restrict__ sa_b, const float* __restrict__ self_w,
    const float* __restrict__ pool_w, const float* __restrict__ ent0_w,
    const float* __restrict__ ent1_w, const float* __restrict__ w_ih,
    const float* __restrict__ w_hh,
    short* __restrict__ wq, short* __restrict__ Wf,
    short* __restrict__ We0, short* __restrict__ We1,
    short* __restrict__ wos, float* __restrict__ bos,
    short* __restrict__ wihb, short* __restrict__ whhb,
    short* __restrict__ wp2)
{
    int i = blockIdx.x * 256 + threadIdx.x;
    if (i < 12288) wq[i] = f2bs(inp_w[i]);
    if (i < 65536) { wihb[i] = f2bs(w_ih[i]); whhb[i] = f2bs(w_hh[i]); }
    if (i < 8192) { int c = i >> 6, k = i & 63; wp2[i] = f2bs(pool_w[(size_t)c * 354 + 290 + k]); }
    if (i < 4096) {
        int c = i >> 6, k = i & 63;
        float s = 0.f;
        for (int j = 0; j < 64; ++j) s = fmaf(sa_w[c * 64 + j], outp_w[j * 64 + k], s);
        wos[i] = f2bs(s);
    }
    if (i < 64) {
        float s = sa_b[i];
        for (int j = 0; j < 64; ++j) s = fmaf(sa_w[i * 64 + j], outp_b[j], s);
        bos[i] = s;
    }
    if (i < 1024) {
        int cp = i >> 4, k = i & 15;
        int ct = cp >> 4, lr2 = cp & 15;
        int e = 32 * (ct >> 1) + 2 * lr2 + (ct & 1);   // even/odd remap
        We0[i] = f2bs(k < 12 ? ent0_w[e * 302 + k] : 0.f);
        We1[i] = f2bs(k < 8 ? ent1_w[e * 298 + k] : 0.f);
    }
    if (i < 102400) {
        int c = i / 320, k = i - c * 320;
        float v = 0.f;
        if (k < 290) {
            if (c < 64) v = self_w[c * 580 + k] + self_w[c * 580 + 290 + k];
            else if (c < 192) v = pool_w[(size_t)(c - 64) * 354 + k];
            else if (c < 256) v = ent0_w[(c - 192) * 302 + 12 + k];
            else v = ent1_w[(c - 256) * 298 + 8 + k];
        }
        Wf[i] = f2bs(v);
    }
}

// ---------------------------------------------------------------------------
// k_frontN: MFMA front end (unchanged from round 13).
// ---------------------------------------------------------------------------
#define FN_XSB 0
#define FN_XP0 16384
#define FN_XP1 20736
#define FN_TOTAL 25088

__global__ __launch_bounds__(256, 4) void k_frontN(
    const float* __restrict__ xag, const float* __restrict__ xlid,
    const float* __restrict__ xsz, const float* __restrict__ xe0,
    const float* __restrict__ xe1,
    const float* __restrict__ conv_w, const float* __restrict__ conv_b,
    const float* __restrict__ self_b, const float* __restrict__ ent0_b,
    const float* __restrict__ ent1_b,
    const short* __restrict__ Wf, const short* __restrict__ We0,
    const short* __restrict__ We1,
    __hip_bfloat16* __restrict__ z_ent, float* __restrict__ zin_x)
{
    extern __shared__ char smem[];
    char* xsb = smem + FN_XSB;
    float* xp0f = (float*)(smem + FN_XP0);
    float* xp1f = (float*)(smem + FN_XP1);
    char* ae = smem + FN_XSB;
    float* lidf = (float*)(smem + FN_XP0);

    const int tid = threadIdx.x;
    const int s0 = blockIdx.x * FN_SB;
    const int wv = __builtin_amdgcn_readfirstlane(tid >> 6);
    const int l = tid & 63;
    const int lr = l & 15;
    const int lg = l >> 4;

    for (int i = tid; i < FN_SB * 32; i += 256) {
        int d = i & 31, sl = i >> 5;
        lidf[d * 18 + sl] = xlid[(size_t)s0 * 32 + i];
    }
    for (int i = tid; i < FN_SB * 16; i += 256) {
        int sl = i >> 4, d = i & 15;
        *(short*)(xsb + ((sl * 640 + d * 2) ^ ((sl & 7) << 4))) = f2bs(xag[(size_t)s0 * 16 + i]);
    }
    for (int i = tid; i < FN_SB * 4; i += 256) {
        int sl = i >> 2, d = i & 3;
        *(short*)(xsb + ((sl * 640 + (286 + d) * 2) ^ ((sl & 7) << 4))) = f2bs(xsz[(size_t)s0 * 4 + i]);
    }
    for (int i = tid; i < FN_SB * 30; i += 256) {
        int sl = i / 30, d = 290 + (i - (i / 30) * 30);
        *(short*)(xsb + ((sl * 640 + d * 2) ^ ((sl & 7) << 4))) = 0;
    }
    __syncthreads();
    #pragma unroll
    for (int c = 0; c < 9; ++c) {
        float w0 = conv_w[c * 3], w1 = conv_w[c * 3 + 1], w2 = conv_w[c * 3 + 2];
        float bb = conv_b[c];
        for (int i = tid; i < 30 * FN_SB; i += 256) {
            int p = i >> 4, sl = i & 15;
            float v = bb + w0 * lidf[p * 18 + sl] + w1 * lidf[(p + 1) * 18 + sl]
                    + w2 * lidf[(p + 2) * 18 + sl];
            *(short*)(xsb + ((sl * 640 + (16 + c * 30 + p) * 2) ^ ((sl & 7) << 4))) = f2bs(fmaxf(v, 0.f));
        }
    }
    __syncthreads();

    f32x4 acc[5];
    #pragma unroll
    for (int c = 0; c < 5; ++c) acc[c] = (f32x4){0.f, 0.f, 0.f, 0.f};

    for (int kk = 0; kk < 10; ++kk) {
        short8 af = *(const short8*)(xsb + ((lr * 640 + kk * 64 + lg * 16) ^ ((lr & 7) << 4)));
        short8 bf[5];
        #pragma unroll
        for (int c = 0; c < 5; ++c) {
            int col = (wv * 5 + c) * 16 + lr;
            bf[c] = *(const short8*)(Wf + (size_t)col * 320 + kk * 32 + lg * 8);
        }
        #pragma unroll
        for (int c = 0; c < 5; ++c)
            acc[c] = __builtin_amdgcn_mfma_f32_16x16x32_bf16(af, bf[c], acc[c], 0, 0, 0);
    }

    #pragma unroll
    for (int c = 0; c < 5; ++c) {
        int ct = wv * 5 + c;
        int gc = ct * 16 + lr;
        int rowb = lg * 4;
        f32x4 a = acc[c];
        if (ct * 16 < 64) {
            float bias = self_b[gc];
            #pragma unroll
            for (int r = 0; r < 4; ++r)
                z_ent[(size_t)(s0 + rowb + r) * 2112 + gc] = __float2bfloat16(fmaxf(a[r] + bias, 0.f));
        } else if (ct * 16 < 192) {
            int r2 = gc - 64;
            #pragma unroll
            for (int r = 0; r < 4; ++r)
                zin_x[(size_t)(s0 + rowb + r) * 128 + r2] = a[r];
        } else if (ct * 16 < 256) {
            float bias = ent0_b[gc - 192];
            #pragma unroll
            for (int r = 0; r < 4; ++r)
                xp0f[(rowb + r) * 68 + (gc - 192)] = a[r] + bias;
        } else {
            float bias = ent1_b[gc - 256];
            #pragma unroll
            for (int r = 0; r < 4; ++r)
                xp1f[(rowb + r) * 68 + (gc - 256)] = a[r] + bias;
        }
    }
    __syncthreads();

    // ---- ent0 MLP ----
    {
        short8 bz = {0, 0, 0, 0, 0, 0, 0, 0};
        short8 be[4];
        #pragma unroll
        for (int ct = 0; ct < 4; ++ct) {
            int col = ct * 16 + lr;
            short8 bv = *(const short8*)(We0 + col * 16 + (lg & 1) * 8);
            be[ct] = (lg < 2) ? bv : bz;
        }
        for (int i = tid; i < 4096; i += 256) ((uint32*)ae)[i] = 0;
        __syncthreads();
        {
            int sl = tid >> 4, n = tid & 15;
            int row = sl * 16 + n;
            int sw = (row & 3) << 4;
            const float4* src = (const float4*)(xe0 + (size_t)(s0 + sl) * 192 + n * 12);
            float4 v0 = src[0], v1 = src[1], v2 = src[2];
            *(uint32*)(ae + ((row * 64 + 0) ^ sw))  = pkbf(v0.x, v0.y);
            *(uint32*)(ae + ((row * 64 + 4) ^ sw))  = pkbf(v0.z, v0.w);
            *(uint32*)(ae + ((row * 64 + 8) ^ sw))  = pkbf(v1.x, v1.y);
            *(uint32*)(ae + ((row * 64 + 12) ^ sw)) = pkbf(v1.z, v1.w);
            *(uint32*)(ae + ((row * 64 + 16) ^ sw)) = pkbf(v2.x, v2.y);
            *(uint32*)(ae + ((row * 64 + 20) ^ sw)) = pkbf(v2.z, v2.w);
        }
        __syncthreads();
        #pragma unroll
        for (int j = 0; j < 4; ++j) {
            int gs = wv * 4 + j;
            int row = gs * 16 + lr;
            short8 af = *(const short8*)(ae + ((row * 64 + lg * 16) ^ ((row & 3) << 4)));
            f32x4 a2[4];
            #pragma unroll
            for (int ct = 0; ct < 4; ++ct) {
                f32x4 z = {0.f, 0.f, 0.f, 0.f};
                a2[ct] = __builtin_amdgcn_mfma_f32_16x16x32_bf16(af, be[ct], z, 0, 0, 0);
            }
            #pragma unroll
            for (int t = 0; t < 2; ++t) {
                int e0 = 32 * t + 2 * lr;
                float xv0 = xp0f[gs * 68 + e0];
                float xv1 = xp0f[gs * 68 + e0 + 1];
                #pragma unroll
                for (int r = 0; r < 4; ++r) {
                    int n = lg * 4 + r;
                    float v0 = fmaxf(a2[2 * t][r] + xv0, 0.f);
                    float v1 = fmaxf(a2[2 * t + 1][r] + xv1, 0.f);
                    *(uint32*)((char*)z_ent + ((size_t)(s0 + gs) * 2112 + (1 + n) * 64 + e0) * 2) = pkbf(v0, v1);
                }
            }
        }
        __syncthreads();
    }

    // ---- ent1 MLP ----
    {
        short8 bz = {0, 0, 0, 0, 0, 0, 0, 0};
        short8 be[4];
        #pragma unroll
        for (int ct = 0; ct < 4; ++ct) {
            int col = ct * 16 + lr;
            short8 bv = *(const short8*)(We1 + col * 16 + (lg & 1) * 8);
            be[ct] = (lg < 2) ? bv : bz;
        }
        for (int i = tid; i < 4096; i += 256) ((uint32*)ae)[i] = 0;
        __syncthreads();
        {
            int sl = tid >> 4, n = tid & 15;
            int row = sl * 16 + n;
            int sw = (row & 3) << 4;
            const float4* src = (const float4*)(xe1 + (size_t)(s0 + sl) * 128 + n * 8);
            float4 v0 = src[0], v1 = src[1];
            *(uint32*)(ae + ((row * 64 + 0) ^ sw))  = pkbf(v0.x, v0.y);
            *(uint32*)(ae + ((row * 64 + 4) ^ sw))  = pkbf(v0.z, v0.w);
            *(uint32*)(ae + ((row * 64 + 8) ^ sw))  = pkbf(v1.x, v1.y);
            *(uint32*)(ae + ((row * 64 + 12) ^ sw)) = pkbf(v1.z, v1.w);
        }
        __syncthreads();
        #pragma unroll
        for (int j = 0; j < 4; ++j) {
            int gs = wv * 4 + j;
            int row = gs * 16 + lr;
            short8 af = *(const short8*)(ae + ((row * 64 + lg * 16) ^ ((row & 3) << 4)));
            f32x4 a2[4];
            #pragma unroll
            for (int ct = 0; ct < 4; ++ct) {
                f32x4 z = {0.f, 0.f, 0.f, 0.f};
                a2[ct] = __builtin_amdgcn_mfma_f32_16x16x32_bf16(af, be[ct], z, 0, 0, 0);
            }
            #pragma unroll
            for (int t = 0; t < 2; ++t) {
                int e0 = 32 * t + 2 * lr;
                float xv0 = xp1f[gs * 68 + e0];
                float xv1 = xp1f[gs * 68 + e0 + 1];
                #pragma unroll
                for (int r = 0; r < 4; ++r) {
                    int n = lg * 4 + r;
                    float v0 = fmaxf(a2[2 * t][r] + xv0, 0.f);
                    float v1 = fmaxf(a2[2 * t + 1][r] + xv1, 0.f);
                    *(uint32*)((char*)z_ent + ((size_t)(s0 + gs) * 2112 + (17 + n) * 64 + e0) * 2) = pkbf(v0, v1);
                }
            }
        }
    }
}

// ---------------------------------------------------------------------------
// k_attnG: full-MFMA attention. Wave wv owns head wv (Q=ct wv, K=ct wv+4,
// V=ct wv+8). Q/K MFMA operand-swapped -> packed short4 d-contiguous stores;
// V original order -> packed short4 q-contiguous stores. P2b swapped too.
// ---------------------------------------------------------------------------
#define AG_QB   0
#define AG_KB   4224
#define AG_VT   8448
#define AG_PW   12544
#define AG_P32  16640
#define AG_V32  17408
#define AG_MSK  17664
#define AG_TOTAL 17824

__global__ __launch_bounds__(256, 8) void k_attnG(
    const __hip_bfloat16* __restrict__ z_ent,
    const int* __restrict__ mask0, const int* __restrict__ mask1,
    const short* __restrict__ wqkvb, const float* __restrict__ inp_b,
    const short* __restrict__ wos_g, const float* __restrict__ bos_g,
    float* __restrict__ pooled_ws)
{
    extern __shared__ char smem[];
    char*  Qb  = smem + AG_QB;
    char*  Kb  = smem + AG_KB;
    char*  Vt  = smem + AG_VT;
    char*  Pw  = smem + AG_PW;
    float* P32 = (float*)(smem + AG_P32);
    float* V32 = (float*)(smem + AG_V32);
    float* msk = (float*)(smem + AG_MSK);
    char*  ob  = Qb;

    const int tid = threadIdx.x;
    const int s = blockIdx.x;
    const short* zg = (const short*)(z_ent + (size_t)s * 2112);

    if (tid < 16) msk[1 + tid] = (float)mask0[(size_t)s * 16 + tid];
    else if (tid < 32) msk[17 + (tid - 16)] = (float)mask1[(size_t)s * 16 + (tid - 16)];
    else if (tid == 32) msk[0] = 1.0f;

    const int wv = __builtin_amdgcn_readfirstlane(tid >> 6);
    const int l  = tid & 63;
    const int lr = l & 15;
    const int lg = l >> 4;

    // ---- P1: in_proj GEMM, per-head tiles, packed epilogue stores ----
    {
        int colQ = wv * 16 + lr;
        short8 wQ0 = *(const short8*)(wqkvb + colQ * 64 + lg * 8);
        short8 wQ1 = *(const short8*)(wqkvb + colQ * 64 + 32 + lg * 8);
        int colK = (wv + 4) * 16 + lr;
        short8 wK0 = *(const short8*)(wqkvb + colK * 64 + lg * 8);
        short8 wK1 = *(const short8*)(wqkvb + colK * 64 + 32 + lg * 8);
        int colV = (wv + 8) * 16 + lr;
        short8 wV0 = *(const short8*)(wqkvb + colV * 64 + lg * 8);
        short8 wV1 = *(const short8*)(wqkvb + colV * 64 + 32 + lg * 8);
        float4 bQ = *(const float4*)(inp_b + wv * 16 + lg * 4);
        float4 bK = *(const float4*)(inp_b + 64 + wv * 16 + lg * 4);
        float biasV = inp_b[128 + wv * 16 + lr];
        for (int rt = 0; rt < 3; ++rt) {
            int arow = rt * 16 + lr;
            if (arow > 32) arow = 32;
            short8 a0 = *(const short8*)(zg + arow * 64 + lg * 8);
            short8 a1 = *(const short8*)(zg + arow * 64 + 32 + lg * 8);
            f32x4 z4 = {0.f, 0.f, 0.f, 0.f};
            f32x4 aQ = __builtin_amdgcn_mfma_f32_16x16x32_bf16(wQ0, a0, z4, 0, 0, 0);
            aQ = __builtin_amdgcn_mfma_f32_16x16x32_bf16(wQ1, a1, aQ, 0, 0, 0);
            f32x4 aK = __builtin_amdgcn_mfma_f32_16x16x32_bf16(wK0, a0, z4, 0, 0, 0);
            aK = __builtin_amdgcn_mfma_f32_16x16x32_bf16(wK1, a1, aK, 0, 0, 0);
            f32x4 aV = __builtin_amdgcn_mfma_f32_16x16x32_bf16(a0, wV0, z4, 0, 0, 0);
            aV = __builtin_amdgcn_mfma_f32_16x16x32_bf16(a1, wV1, aV, 0, 0, 0);
            int q = rt * 16 + lr;
            if (q < 33) {
                short4 st;
                st.x = f2bs(aQ[0] + bQ.x); st.y = f2bs(aQ[1] + bQ.y);
                st.z = f2bs(aQ[2] + bQ.z); st.w = f2bs(aQ[3] + bQ.w);
                *(short4*)(Qb + (wv * 33 + q) * 32 + lg * 8) = st;
                st.x = f2bs(aK[0] + bK.x); st.y = f2bs(aK[1] + bK.y);
                st.z = f2bs(aK[2] + bK.z); st.w = f2bs(aK[3] + bK.w);
                *(short4*)(Kb + (wv * 33 + q) * 32 + lg * 8) = st;
            }
            if (rt < 2) {
                int q0 = rt * 16 + lg * 4;
                short4 sv;
                sv.x = f2bs(aV[0] + biasV); sv.y = f2bs(aV[1] + biasV);
                sv.z = f2bs(aV[2] + biasV); sv.w = f2bs(aV[3] + biasV);
                *(short4*)(Vt + (wv * 16 + lr) * 64 + ((q0 * 2) ^ pswz(lr))) = sv;
            } else if (lg == 0) {
                V32[wv * 16 + lr] = aV[0] + biasV;
            }
        }
    }
    __syncthreads();

    // ---- P2a: QK MFMA + mask-folded softmax; P packed in regs ----
    uint32 pk[3][4];
    {
        const short8 zero8 = {0, 0, 0, 0, 0, 0, 0, 0};
        short8 kf[3];
        #pragma unroll
        for (int t = 0; t < 3; ++t)
            kf[t] = (lg < 2) ? *(const short8*)(Kb + ((wv * 33 + t * 16 + lr) * 32) + lg * 16) : zero8;
        float mk0 = msk[lr];
        float mk1 = msk[16 + lr];
        float mk2 = (lr == 0) ? msk[32] : 0.f;
        float sc0 = mk0 * 0.25f, bo0 = (mk0 - 1.f) * 40.f;
        float sc1 = mk1 * 0.25f, bo1 = (mk1 - 1.f) * 40.f;
        float sc2 = mk2 * 0.25f, bo2 = (mk2 - 1.f) * 40.f;
        #pragma unroll
        for (int qt = 0; qt < 3; ++qt) {
            short8 qf = (lg < 2) ? *(const short8*)(Qb + ((wv * 33 + qt * 16 + lr) * 32) + lg * 16) : zero8;
            f32x4 z = {0.f, 0.f, 0.f, 0.f};
            f32x4 S0 = __builtin_amdgcn_mfma_f32_16x16x32_bf16(qf, kf[0], z, 0, 0, 0);
            f32x4 S1 = __builtin_amdgcn_mfma_f32_16x16x32_bf16(qf, kf[1], z, 0, 0, 0);
            f32x4 S2 = __builtin_amdgcn_mfma_f32_16x16x32_bf16(qf, kf[2], z, 0, 0, 0);
            #pragma unroll
            for (int r = 0; r < 4; ++r) {
                float e0 = __expf(fmaf(S0[r], sc0, bo0));
                float e1 = __expf(fmaf(S1[r], sc1, bo1));
                float e2 = __expf(fmaf(S2[r], sc2, bo2));
                float sm = e0 + e1 + e2;
                sm += __shfl_xor(sm, 1);
                sm += __shfl_xor(sm, 2);
                sm += __shfl_xor(sm, 4);
                sm += __shfl_xor(sm, 8);
                float inv = 1.0f / sm;
                pk[qt][r] = pkbf(e0 * inv, e1 * inv);
                if (lr == 0) P32[wv * 48 + qt * 16 + lg * 4 + r] = e2 * inv;
            }
        }
    }
    __syncthreads();   // all Qb/Kb reads done; ob may overwrite Qb

    // ---- P2b: PV MFMA (swapped: D[d][q]); packed short4 ob stores ----
    {
        short8 vf = *(const short8*)(Vt + (wv * 16 + lr) * 64 + ((lg * 16) ^ pswz(lr)));
        float4 v32v = *(const float4*)(V32 + wv * 16 + lg * 4);
        f32x4 C[3];
        #pragma unroll
        for (int qt = 0; qt < 3; ++qt) {
            #pragma unroll
            for (int r = 0; r < 4; ++r) {
                int ql = lg * 4 + r;
                uint32 p = pk[qt][r];
                char* prow = Pw + wv * 1024 + ql * 64;
                int sz = pswz(ql);
                *(short*)(prow + ((lr * 2) ^ sz)) = (short)(p & 0xffffu);
                *(short*)(prow + (((16 + lr) * 2) ^ sz)) = (short)(p >> 16);
            }
            short8 pf = *(const short8*)(Pw + wv * 1024 + lr * 64 + ((lg * 16) ^ pswz(lr)));
            f32x4 z = {0.f, 0.f, 0.f, 0.f};
            C[qt] = __builtin_amdgcn_mfma_f32_16x16x32_bf16(vf, pf, z, 0, 0, 0);
        }
        #pragma unroll
        for (int qt = 0; qt < 3; ++qt) {
            int q = qt * 16 + lr;
            if (q <= 32) {
                float p32 = P32[wv * 48 + q];
                short4 o;
                o.x = f2bs(C[qt][0] + p32 * v32v.x);
                o.y = f2bs(C[qt][1] + p32 * v32v.y);
                o.z = f2bs(C[qt][2] + p32 * v32v.z);
                o.w = f2bs(C[qt][3] + p32 * v32v.w);
                *(short4*)(ob + ((q * 128 + (wv * 16 + lg * 4) * 2) ^ ((q & 7) << 4))) = o;
            }
        }
    }
    __syncthreads();

    // ---- P4: fused (sa@out_proj) GEMM + residual + mask; pooled -> ws ----
    {
        int col = wv * 16 + lr;
        short8 b0 = *(const short8*)(wos_g + col * 64 + lg * 8);
        short8 b1 = *(const short8*)(wos_g + col * 64 + 32 + lg * 8);
        float bias = bos_g[col];
        float ps = 0.f;
        for (int rt = 0; rt < 3; ++rt) {
            int arow = rt * 16 + lr;
            int sw = (arow & 7) << 4;
            short8 a0 = *(const short8*)(ob + ((arow * 128 + lg * 16) ^ sw));
            short8 a1 = *(const short8*)(ob + ((arow * 128 + 64 + lg * 16) ^ sw));
            f32x4 acc = {0.f, 0.f, 0.f, 0.f};
            acc = __builtin_amdgcn_mfma_f32_16x16x32_bf16(a0, b0, acc, 0, 0, 0);
            acc = __builtin_amdgcn_mfma_f32_16x16x32_bf16(a1, b1, acc, 0, 0, 0);
            int rb = rt * 16 + lg * 4;
            #pragma unroll
            for (int r = 0; r < 4; ++r) {
                int row = rb + r;
                if (row < 33) {
                    float zev = bf2f(*(const unsigned short*)(zg + row * 64 + col));
                    ps += msk[row] * (zev + fmaxf(acc[r] + bias, 0.f));
                }
            }
        }
        ps += __shfl_xor(ps, 16); ps += __shfl_xor(ps, 32);
        if (lg == 0) pooled_ws[(size_t)s * 64 + col] = ps * (1.0f / 33.0f);
    }
}

// ---------------------------------------------------------------------------
// k_zinx: fused zin + x-projection (unchanged).
// ---------------------------------------------------------------------------
__global__ __launch_bounds__(256, 2) void k_zinx(
    const float* __restrict__ pooled_ws, const float* __restrict__ zin_x,
    const short* __restrict__ wp2, const float* __restrict__ pool_b,
    const short* __restrict__ wihb, const float* __restrict__ b_ih,
    const float* __restrict__ b_hh, short* __restrict__ xp)
{
    extern __shared__ char smem[];
    char* A1 = smem;
    char* zt = smem + 8192;
    const int tid = threadIdx.x;
    const size_t r0 = (size_t)blockIdx.x * 64;

    for (int i = tid; i < 2048; i += 256) {
        int sl = i >> 5, dp = i & 31;
        float2 v = ((const float2*)(pooled_ws + (r0 + sl) * 64))[dp];
        *(uint32*)(A1 + ((sl * 128 + dp * 4) ^ ((sl & 7) << 4))) = pkbf(v.x, v.y);
    }
    __syncthreads();

    const int wv = __builtin_amdgcn_readfirstlane(tid >> 6);
    const int l = tid & 63;
    const int lr = l & 15;
    const int lg = l >> 4;

    #pragma unroll
    for (int c = 0; c < 2; ++c) {
        int col = (wv * 2 + c) * 16 + lr;
        short8 bf0 = *(const short8*)(wp2 + col * 64 + lg * 8);
        short8 bf1 = *(const short8*)(wp2 + col * 64 + 32 + lg * 8);
        float bias = pool_b[col];
        #pragma unroll
        for (int rt = 0; rt < 4; ++rt) {
            int row16 = rt * 16 + lr;
            short8 a0 = *(const short8*)(A1 + ((row16 * 128 + lg * 16) ^ ((row16 & 7) << 4)));
            short8 a1 = *(const short8*)(A1 + ((row16 * 128 + 64 + lg * 16) ^ ((row16 & 7) << 4)));
            f32x4 acc = {0.f, 0.f, 0.f, 0.f};
            acc = __builtin_amdgcn_mfma_f32_16x16x32_bf16(a0, bf0, acc, 0, 0, 0);
            acc = __builtin_amdgcn_mfma_f32_16x16x32_bf16(a1, bf1, acc, 0, 0, 0);
            #pragma unroll
            for (int r = 0; r < 4; ++r) {
                int row = rt * 16 + lg * 4 + r;
                float v = fmaxf(acc[r] + bias + zin_x[(r0 + row) * 128 + col], 0.f);
                *(short*)(zt + ((row * 256 + col * 2) ^ ((row & 7) << 4))) = f2bs(v);
            }
        }
    }
    __syncthreads();

    short8 af[4][4];
    #pragma unroll
    for (int rt = 0; rt < 4; ++rt)
        #pragma unroll
        for (int kc = 0; kc < 4; ++kc) {
            int row = rt * 16 + lr;
            af[rt][kc] = *(const short8*)(zt + ((row * 256 + kc * 64 + lg * 16) ^ ((row & 7) << 4)));
        }

    for (int ct8 = 0; ct8 < 8; ++ct8) {
        int ct = wv * 8 + ct8;
        int col = ct * 16 + lr;
        short8 bf[4];
        #pragma unroll
        for (int kc = 0; kc < 4; ++kc)
            bf[kc] = *(const short8*)(wihb + (size_t)col * 128 + kc * 32 + lg * 8);
        float bias = b_ih[col] + b_hh[col];
        int g = col >> 7, j = col & 127;
        #pragma unroll
        for (int rt = 0; rt < 4; ++rt) {
            f32x4 acc = {0.f, 0.f, 0.f, 0.f};
            #pragma unroll
            for (int kc = 0; kc < 4; ++kc)
                acc = __builtin_amdgcn_mfma_f32_16x16x32_bf16(af[rt][kc], bf[kc], acc, 0, 0, 0);
            #pragma unroll
            for (int r = 0; r < 4; ++r)
                xp[(r0 + rt * 16 + lg * 4 + r) * 512 + j * 4 + g] = f2bs(acc[r] + bias);
        }
    }
}

// ---------------------------------------------------------------------------
// k_lstm2: MFMA recurrent scan, double-buffered h -> 1 barrier/step.
// ---------------------------------------------------------------------------
__global__ __launch_bounds__(512, 1) void k_lstm2(
    const short* __restrict__ xp, const short* __restrict__ whhb,
    const int* __restrict__ done, float* __restrict__ h_all)
{
    __shared__ short hl[2][16 * 128];
    __shared__ float keepl[64 * 16];
    const int tid = threadIdx.x;
    const int s0 = blockIdx.x * 16;
    const int wv = __builtin_amdgcn_readfirstlane(tid >> 6);
    const int l = tid & 63;
    const int lr = l & 15;
    const int lg = l >> 4;

    for (int i = tid; i < 1024; i += 512) {
        int t = i >> 4, ls = i & 15;
        keepl[i] = done[t * 32 + ((s0 + ls) >> 3)] ? 0.f : 1.f;
    }
    for (int i = tid; i < 1024; i += 512) ((uint32*)hl[0])[i] = 0;

    short8 bf[4][4];
    #pragma unroll
    for (int gi = 0; gi < 4; ++gi) {
        int col = (gi * 8 + wv) * 16 + lr;
        #pragma unroll
        for (int kc = 0; kc < 4; ++kc)
            bf[gi][kc] = *(const short8*)(whhb + (size_t)col * 128 + kc * 32 + lg * 8);
    }
    float c0 = 0.f, c1 = 0.f, c2 = 0.f, c3 = 0.f;
    const int jcol = wv * 16 + lr;

    short4 xn[4];
    #pragma unroll
    for (int r = 0; r < 4; ++r)
        xn[r] = *(const short4*)(xp + ((size_t)(s0 + lg * 4 + r)) * 512 + jcol * 4);
    __syncthreads();

    for (int t = 0; t < T_DIM; ++t) {
        char* hr = (char*)hl[t & 1];
        char* hw = (char*)hl[(t + 1) & 1];
        short4 xc[4];
        #pragma unroll
        for (int r = 0; r < 4; ++r) xc[r] = xn[r];
        if (t < 63) {
            #pragma unroll
            for (int r = 0; r < 4; ++r)
                xn[r] = *(const short4*)(xp + ((size_t)(t + 1) * 256 + s0 + lg * 4 + r) * 512 + jcol * 4);
        }
        short8 af[4];
        #pragma unroll
        for (int kc = 0; kc < 4; ++kc)
            af[kc] = *(const short8*)(hr + ((lr * 256 + kc * 64 + lg * 16) ^ ((lr & 7) << 4)));
        f32x4 z = {0.f, 0.f, 0.f, 0.f};
        f32x4 Ci = z, Cf = z, Cg = z, Co = z;
        #pragma unroll
        for (int kc = 0; kc < 4; ++kc) {
            Ci = __builtin_amdgcn_mfma_f32_16x16x32_bf16(af[kc], bf[0][kc], Ci, 0, 0, 0);
            Cf = __builtin_amdgcn_mfma_f32_16x16x32_bf16(af[kc], bf[1][kc], Cf, 0, 0, 0);
            Cg = __builtin_amdgcn_mfma_f32_16x16x32_bf16(af[kc], bf[2][kc], Cg, 0, 0, 0);
            Co = __builtin_amdgcn_mfma_f32_16x16x32_bf16(af[kc], bf[3][kc], Co, 0, 0, 0);
        }

        #pragma unroll
        for (int r = 0; r < 4; ++r) {
            int sl = lg * 4 + r;
            float kt = keepl[t * 16 + sl];
            float gi = bf2f((unsigned short)xc[r].x) + Ci[r];
            float gf = bf2f((unsigned short)xc[r].y) + Cf[r];
            float gg = bf2f((unsigned short)xc[r].z) + Cg[r];
            float go = bf2f((unsigned short)xc[r].w) + Co[r];
            float cc = (r == 0 ? c0 : r == 1 ? c1 : r == 2 ? c2 : c3) * kt;
            cc = sigf(gf) * cc + sigf(gi) * tanhf(gg);
            float hn = sigf(go) * tanhf(cc);
            if (r == 0) c0 = cc; else if (r == 1) c1 = cc; else if (r == 2) c2 = cc; else c3 = cc;
            float kn = (t < 63) ? keepl[(t + 1) * 16 + sl] : 1.f;
            *(short*)(hw + ((sl * 256 + jcol * 2) ^ ((sl & 7) << 4))) = f2bs(hn * kn);
            h_all[((size_t)t * 256 + s0 + sl) * 128 + jcol] = hn;
        }
        __syncthreads();
    }
}

// ---------------------------------------------------------------------------
// Kernel: categorical heads (unchanged)
// ---------------------------------------------------------------------------
__global__ __launch_bounds__(256) void k_heads(
    const float* __restrict__ h_all, const int* __restrict__ actions,
    const float* __restrict__ h0w, const float* __restrict__ h0b,
    const float* __restrict__ h1w, const float* __restrict__ h1b,
    float* __restrict__ out)
{
    __shared__ float w0[640], w1[640], b0[8], b1[8];
    const int tid = threadIdx.x;
    for (int i = tid; i < 640; i += 256) { w0[i] = h0w[i]; w1[i] = h1w[i]; }
    if (tid < 5) { b0[tid] = h0b[tid]; b1[tid] = h1b[tid]; }
    __syncthreads();
    const int g = blockIdx.x * 256 + tid;
    const float* h = h_all + (size_t)g * 128;
    float l0[5], l1[5];
    #pragma unroll
    for (int cc = 0; cc < 5; ++cc) { l0[cc] = b0[cc]; l1[cc] = b1[cc]; }
    for (int j = 0; j < 128; ++j) {
        float hv = h[j];
        #pragma unroll
        for (int cc = 0; cc < 5; ++cc) {
            l0[cc] = fmaf(w0[cc * 128 + j], hv, l0[cc]);
            l1[cc] = fmaf(w1[cc * 128 + j], hv, l1[cc]);
        }
    }
    int a0 = actions[(size_t)g * 2], a1 = actions[(size_t)g * 2 + 1];
    float m0 = l0[0], m1 = l1[0];
    #pragma unroll
    for (int cc = 1; cc < 5; ++cc) { m0 = fmaxf(m0, l0[cc]); m1 = fmaxf(m1, l1[cc]); }
    float s0 = 0.f, s1 = 0.f;
    #pragma unroll
    for (int cc = 0; cc < 5; ++cc) { s0 += expf(l0[cc] - m0); s1 += expf(l1[cc] - m1); }
    float lse0 = m0 + logf(s0), lse1 = m1 + logf(s1);
    float ent0 = 0.f, ent1 = 0.f, lp0 = 0.f, lp1 = 0.f;
    #pragma unroll
    for (int cc = 0; cc < 5; ++cc) {
        float p0 = l0[cc] - lse0, p1 = l1[cc] - lse1;
        ent0 -= expf(p0) * p0;
        ent1 -= expf(p1) * p1;
        if (cc == a0) lp0 = p0;
        if (cc == a1) lp1 = p1;
    }
    out[ACT_OFF + (size_t)g * 2]     = (float)a0;
    out[ACT_OFF + (size_t)g * 2 + 1] = (float)a1;
    out[LP_OFF + g]                  = lp0 * lp1;
    out[ENT_OFF + (size_t)g * 2]     = ent0;
    out[ENT_OFF + (size_t)g * 2 + 1] = ent1;
}

extern "C" void kernel_launch(void* const* d_in, const int* in_sizes, int n_in,
                              void* d_out, int out_size, void* d_ws, size_t ws_size,
                              hipStream_t stream)
{
    const float* x_agent = (const float*)d_in[0];
    const float* x_lidar = (const float*)d_in[1];
    const float* x_safe  = (const float*)d_in[2];
    const float* x_ent0  = (const float*)d_in[3];
    const float* x_ent1  = (const float*)d_in[4];
    const int*   mask0   = (const int*)d_in[5];
    const int*   mask1   = (const int*)d_in[6];
    const int*   done    = (const int*)d_in[7];
    const int*   actions = (const int*)d_in[8];
    const float* conv_w  = (const float*)d_in[9];
    const float* conv_b  = (const float*)d_in[10];
    const float* self_w  = (const float*)d_in[11];
    const float* self_b  = (const float*)d_in[12];
    const float* ent0_w  = (const float*)d_in[13];
    const float* ent0_b  = (const float*)d_in[14];
    const float* ent1_w  = (const float*)d_in[15];
    const float* ent1_b  = (const float*)d_in[16];
    const float* inp_w   = (const float*)d_in[17];
    const float* inp_b   = (const float*)d_in[18];
    const float* outp_w  = (const float*)d_in[19];
    const float* outp_b  = (const float*)d_in[20];
    const float* sa_w    = (const float*)d_in[21];
    const float* sa_b    = (const float*)d_in[22];
    const float* pool_w  = (const float*)d_in[23];
    const float* pool_b  = (const float*)d_in[24];
    const float* w_ih    = (const float*)d_in[25];
    const float* w_hh    = (const float*)d_in[26];
    const float* b_ih    = (const float*)d_in[27];
    const float* b_hh    = (const float*)d_in[28];
    const float* h0w     = (const float*)d_in[29];
    const float* h0b     = (const float*)d_in[30];
    const float* h1w     = (const float*)d_in[31];
    const float* h1b     = (const float*)d_in[32];

    // ws layout
    __hip_bfloat16* z_ent = (__hip_bfloat16*)d_ws;
    float* zin_x  = (float*)((char*)d_ws + (size_t)S_TOT * 2112 * 2);
    float* pooled = zin_x + (size_t)S_TOT * 128;
    float* h_all  = pooled + (size_t)S_TOT * 64;
    short* xp     = (short*)(h_all + (size_t)S_TOT * 128);
    short* wqkvb  = xp + (size_t)S_TOT * 512;
    short* Wf     = wqkvb + 12288;
    short* We0    = Wf + 102400;
    short* We1    = We0 + 1024;
    short* wos    = We1 + 1024;
    float* bos    = (float*)(wos + 4096);
    short* wihb   = (short*)(bos + 64);
    short* whhb   = wihb + 65536;
    short* wp2    = whhb + 65536;

    k_cvt2<<<400, 256, 0, stream>>>(inp_w, outp_w, outp_b, sa_w, sa_b, self_w, pool_w,
                                    ent0_w, ent1_w, w_ih, w_hh,
                                    wqkvb, Wf, We0, We1, wos, bos, wihb, whhb, wp2);

    k_frontN<<<S_TOT / FN_SB, 256, FN_TOTAL, stream>>>(
        x_agent, x_lidar, x_safe, x_ent0, x_ent1,
        conv_w, conv_b, self_b, ent0_b, ent1_b,
        Wf, We0, We1, z_ent, zin_x);

    k_attnG<<<S_TOT, 256, AG_TOTAL, stream>>>(
        z_ent, mask0, mask1, wqkvb, inp_b, wos, bos, pooled);

    k_zinx<<<256, 256, 24576, stream>>>(pooled, zin_x, wp2, pool_b, wihb, b_ih, b_hh, xp);

    k_lstm2<<<16, 512, 0, stream>>>(xp, whhb, done, h_all);

    k_heads<<<S_TOT / 256, 256, 0, stream>>>(h_all, actions, h0w, h0b, h1w, h1b, (float*)d_out);
}

// Round 15
// 315.697 us; speedup vs baseline: 1.0317x; 1.0317x over previous
//
#include <hip/hip_runtime.h>
#include <hip/hip_bf16.h>
#include <math.h>

#define T_DIM 64
#define B_DIM 32
#define S_TOT 16384
#define BA 256
#define FN_SB 16

#define ACT_OFF 0
#define LP_OFF 32768
#define ENT_OFF 49152

typedef __attribute__((ext_vector_type(8))) short short8;
typedef __attribute__((ext_vector_type(4))) float f32x4;
typedef unsigned int uint32;

__device__ __forceinline__ float sigf(float x) { return 1.0f / (1.0f + expf(-x)); }
__device__ __forceinline__ float bf2f(unsigned short u) {
    union { unsigned int i; float f; } a; a.i = ((unsigned int)u) << 16; return a.f;
}
__device__ __forceinline__ uint32 pkbf(float a, float b) {
    __hip_bfloat16 ha = __float2bfloat16(a), hb = __float2bfloat16(b);
    return (uint32)(*(unsigned short*)&ha) | ((uint32)(*(unsigned short*)&hb) << 16);
}
__device__ __forceinline__ short f2bs(float v) {
    __hip_bfloat16 h = __float2bfloat16(v); return *(short*)&h;
}
__device__ __forceinline__ int pswz(int row) { return (((row & 3) ^ ((row >> 2) & 3)) << 4); }

// ---------------------------------------------------------------------------
// k_cvt2: pack all MFMA weights to bf16 (unchanged).
// ---------------------------------------------------------------------------
__global__ __launch_bounds__(256) void k_cvt2(
    const float* __restrict__ inp_w, const float* __restrict__ outp_w,
    const float* __restrict__ outp_b, const float* __restrict__ sa_w,
    const float* __restrict__ sa_b, const float* __restrict__ self_w,
    const float* __restrict__ pool_w, const float* __restrict__ ent0_w,
    const float* __restrict__ ent1_w, const float* __restrict__ w_ih,
    const float* __restrict__ w_hh,
    short* __restrict__ wq, short* __restrict__ Wf,
    short* __restrict__ We0, short* __restrict__ We1,
    short* __restrict__ wos, float* __restrict__ bos,
    short* __restrict__ wihb, short* __restrict__ whhb,
    short* __restrict__ wp2)
{
    int i = blockIdx.x * 256 + threadIdx.x;
    if (i < 12288) wq[i] = f2bs(inp_w[i]);
    if (i < 65536) { wihb[i] = f2bs(w_ih[i]); whhb[i] = f2bs(w_hh[i]); }
    if (i < 8192) { int c = i >> 6, k = i & 63; wp2[i] = f2bs(pool_w[(size_t)c * 354 + 290 + k]); }
    if (i < 4096) {
        int c = i >> 6, k = i & 63;
        float s = 0.f;
        for (int j = 0; j < 64; ++j) s = fmaf(sa_w[c * 64 + j], outp_w[j * 64 + k], s);
        wos[i] = f2bs(s);
    }
    if (i < 64) {
        float s = sa_b[i];
        for (int j = 0; j < 64; ++j) s = fmaf(sa_w[i * 64 + j], outp_b[j], s);
        bos[i] = s;
    }
    if (i < 1024) {
        int cp = i >> 4, k = i & 15;
        int ct = cp >> 4, lr2 = cp & 15;
        int e = 32 * (ct >> 1) + 2 * lr2 + (ct & 1);   // even/odd remap
        We0[i] = f2bs(k < 12 ? ent0_w[e * 302 + k] : 0.f);
        We1[i] = f2bs(k < 8 ? ent1_w[e * 298 + k] : 0.f);
    }
    if (i < 102400) {
        int c = i / 320, k = i - c * 320;
        float v = 0.f;
        if (k < 290) {
            if (c < 64) v = self_w[c * 580 + k] + self_w[c * 580 + 290 + k];
            else if (c < 192) v = pool_w[(size_t)(c - 64) * 354 + k];
            else if (c < 256) v = ent0_w[(c - 192) * 302 + 12 + k];
            else v = ent1_w[(c - 256) * 298 + 8 + k];
        }
        Wf[i] = f2bs(v);
    }
}

// ---------------------------------------------------------------------------
// k_frontN: MFMA front end (round-13 version, unchanged).
// ---------------------------------------------------------------------------
#define FN_XSB 0
#define FN_XP0 16384
#define FN_XP1 20736
#define FN_TOTAL 25088

__global__ __launch_bounds__(256, 4) void k_frontN(
    const float* __restrict__ xag, const float* __restrict__ xlid,
    const float* __restrict__ xsz, const float* __restrict__ xe0,
    const float* __restrict__ xe1,
    const float* __restrict__ conv_w, const float* __restrict__ conv_b,
    const float* __restrict__ self_b, const float* __restrict__ ent0_b,
    const float* __restrict__ ent1_b,
    const short* __restrict__ Wf, const short* __restrict__ We0,
    const short* __restrict__ We1,
    __hip_bfloat16* __restrict__ z_ent, float* __restrict__ zin_x)
{
    extern __shared__ char smem[];
    char* xsb = smem + FN_XSB;
    float* xp0f = (float*)(smem + FN_XP0);
    float* xp1f = (float*)(smem + FN_XP1);
    char* ae = smem + FN_XSB;
    float* lidf = (float*)(smem + FN_XP0);

    const int tid = threadIdx.x;
    const int s0 = blockIdx.x * FN_SB;
    const int wv = __builtin_amdgcn_readfirstlane(tid >> 6);
    const int l = tid & 63;
    const int lr = l & 15;
    const int lg = l >> 4;

    for (int i = tid; i < FN_SB * 32; i += 256) {
        int d = i & 31, sl = i >> 5;
        lidf[d * 18 + sl] = xlid[(size_t)s0 * 32 + i];
    }
    for (int i = tid; i < FN_SB * 16; i += 256) {
        int sl = i >> 4, d = i & 15;
        *(short*)(xsb + ((sl * 640 + d * 2) ^ ((sl & 7) << 4))) = f2bs(xag[(size_t)s0 * 16 + i]);
    }
    for (int i = tid; i < FN_SB * 4; i += 256) {
        int sl = i >> 2, d = i & 3;
        *(short*)(xsb + ((sl * 640 + (286 + d) * 2) ^ ((sl & 7) << 4))) = f2bs(xsz[(size_t)s0 * 4 + i]);
    }
    for (int i = tid; i < FN_SB * 30; i += 256) {
        int sl = i / 30, d = 290 + (i - (i / 30) * 30);
        *(short*)(xsb + ((sl * 640 + d * 2) ^ ((sl & 7) << 4))) = 0;
    }
    __syncthreads();
    #pragma unroll
    for (int c = 0; c < 9; ++c) {
        float w0 = conv_w[c * 3], w1 = conv_w[c * 3 + 1], w2 = conv_w[c * 3 + 2];
        float bb = conv_b[c];
        for (int i = tid; i < 30 * FN_SB; i += 256) {
            int p = i >> 4, sl = i & 15;
            float v = bb + w0 * lidf[p * 18 + sl] + w1 * lidf[(p + 1) * 18 + sl]
                    + w2 * lidf[(p + 2) * 18 + sl];
            *(short*)(xsb + ((sl * 640 + (16 + c * 30 + p) * 2) ^ ((sl & 7) << 4))) = f2bs(fmaxf(v, 0.f));
        }
    }
    __syncthreads();

    f32x4 acc[5];
    #pragma unroll
    for (int c = 0; c < 5; ++c) acc[c] = (f32x4){0.f, 0.f, 0.f, 0.f};

    for (int kk = 0; kk < 10; ++kk) {
        short8 af = *(const short8*)(xsb + ((lr * 640 + kk * 64 + lg * 16) ^ ((lr & 7) << 4)));
        short8 bf[5];
        #pragma unroll
        for (int c = 0; c < 5; ++c) {
            int col = (wv * 5 + c) * 16 + lr;
            bf[c] = *(const short8*)(Wf + (size_t)col * 320 + kk * 32 + lg * 8);
        }
        #pragma unroll
        for (int c = 0; c < 5; ++c)
            acc[c] = __builtin_amdgcn_mfma_f32_16x16x32_bf16(af, bf[c], acc[c], 0, 0, 0);
    }

    #pragma unroll
    for (int c = 0; c < 5; ++c) {
        int ct = wv * 5 + c;
        int gc = ct * 16 + lr;
        int rowb = lg * 4;
        f32x4 a = acc[c];
        if (ct * 16 < 64) {
            float bias = self_b[gc];
            #pragma unroll
            for (int r = 0; r < 4; ++r)
                z_ent[(size_t)(s0 + rowb + r) * 2112 + gc] = __float2bfloat16(fmaxf(a[r] + bias, 0.f));
        } else if (ct * 16 < 192) {
            int r2 = gc - 64;
            #pragma unroll
            for (int r = 0; r < 4; ++r)
                zin_x[(size_t)(s0 + rowb + r) * 128 + r2] = a[r];
        } else if (ct * 16 < 256) {
            float bias = ent0_b[gc - 192];
            #pragma unroll
            for (int r = 0; r < 4; ++r)
                xp0f[(rowb + r) * 68 + (gc - 192)] = a[r] + bias;
        } else {
            float bias = ent1_b[gc - 256];
            #pragma unroll
            for (int r = 0; r < 4; ++r)
                xp1f[(rowb + r) * 68 + (gc - 256)] = a[r] + bias;
        }
    }
    __syncthreads();

    // ---- ent0 MLP ----
    {
        short8 bz = {0, 0, 0, 0, 0, 0, 0, 0};
        short8 be[4];
        #pragma unroll
        for (int ct = 0; ct < 4; ++ct) {
            int col = ct * 16 + lr;
            short8 bv = *(const short8*)(We0 + col * 16 + (lg & 1) * 8);
            be[ct] = (lg < 2) ? bv : bz;
        }
        for (int i = tid; i < 4096; i += 256) ((uint32*)ae)[i] = 0;
        __syncthreads();
        {
            int sl = tid >> 4, n = tid & 15;
            int row = sl * 16 + n;
            int sw = (row & 3) << 4;
            const float4* src = (const float4*)(xe0 + (size_t)(s0 + sl) * 192 + n * 12);
            float4 v0 = src[0], v1 = src[1], v2 = src[2];
            *(uint32*)(ae + ((row * 64 + 0) ^ sw))  = pkbf(v0.x, v0.y);
            *(uint32*)(ae + ((row * 64 + 4) ^ sw))  = pkbf(v0.z, v0.w);
            *(uint32*)(ae + ((row * 64 + 8) ^ sw))  = pkbf(v1.x, v1.y);
            *(uint32*)(ae + ((row * 64 + 12) ^ sw)) = pkbf(v1.z, v1.w);
            *(uint32*)(ae + ((row * 64 + 16) ^ sw)) = pkbf(v2.x, v2.y);
            *(uint32*)(ae + ((row * 64 + 20) ^ sw)) = pkbf(v2.z, v2.w);
        }
        __syncthreads();
        #pragma unroll
        for (int j = 0; j < 4; ++j) {
            int gs = wv * 4 + j;
            int row = gs * 16 + lr;
            short8 af = *(const short8*)(ae + ((row * 64 + lg * 16) ^ ((row & 3) << 4)));
            f32x4 a2[4];
            #pragma unroll
            for (int ct = 0; ct < 4; ++ct) {
                f32x4 z = {0.f, 0.f, 0.f, 0.f};
                a2[ct] = __builtin_amdgcn_mfma_f32_16x16x32_bf16(af, be[ct], z, 0, 0, 0);
            }
            #pragma unroll
            for (int t = 0; t < 2; ++t) {
                int e0 = 32 * t + 2 * lr;
                float xv0 = xp0f[gs * 68 + e0];
                float xv1 = xp0f[gs * 68 + e0 + 1];
                #pragma unroll
                for (int r = 0; r < 4; ++r) {
                    int n = lg * 4 + r;
                    float v0 = fmaxf(a2[2 * t][r] + xv0, 0.f);
                    float v1 = fmaxf(a2[2 * t + 1][r] + xv1, 0.f);
                    *(uint32*)((char*)z_ent + ((size_t)(s0 + gs) * 2112 + (1 + n) * 64 + e0) * 2) = pkbf(v0, v1);
                }
            }
        }
        __syncthreads();
    }

    // ---- ent1 MLP ----
    {
        short8 bz = {0, 0, 0, 0, 0, 0, 0, 0};
        short8 be[4];
        #pragma unroll
        for (int ct = 0; ct < 4; ++ct) {
            int col = ct * 16 + lr;
            short8 bv = *(const short8*)(We1 + col * 16 + (lg & 1) * 8);
            be[ct] = (lg < 2) ? bv : bz;
        }
        for (int i = tid; i < 4096; i += 256) ((uint32*)ae)[i] = 0;
        __syncthreads();
        {
            int sl = tid >> 4, n = tid & 15;
            int row = sl * 16 + n;
            int sw = (row & 3) << 4;
            const float4* src = (const float4*)(xe1 + (size_t)(s0 + sl) * 128 + n * 8);
            float4 v0 = src[0], v1 = src[1];
            *(uint32*)(ae + ((row * 64 + 0) ^ sw))  = pkbf(v0.x, v0.y);
            *(uint32*)(ae + ((row * 64 + 4) ^ sw))  = pkbf(v0.z, v0.w);
            *(uint32*)(ae + ((row * 64 + 8) ^ sw))  = pkbf(v1.x, v1.y);
            *(uint32*)(ae + ((row * 64 + 12) ^ sw)) = pkbf(v1.z, v1.w);
        }
        __syncthreads();
        #pragma unroll
        for (int j = 0; j < 4; ++j) {
            int gs = wv * 4 + j;
            int row = gs * 16 + lr;
            short8 af = *(const short8*)(ae + ((row * 64 + lg * 16) ^ ((row & 3) << 4)));
            f32x4 a2[4];
            #pragma unroll
            for (int ct = 0; ct < 4; ++ct) {
                f32x4 z = {0.f, 0.f, 0.f, 0.f};
                a2[ct] = __builtin_amdgcn_mfma_f32_16x16x32_bf16(af, be[ct], z, 0, 0, 0);
            }
            #pragma unroll
            for (int t = 0; t < 2; ++t) {
                int e0 = 32 * t + 2 * lr;
                float xv0 = xp1f[gs * 68 + e0];
                float xv1 = xp1f[gs * 68 + e0 + 1];
                #pragma unroll
                for (int r = 0; r < 4; ++r) {
                    int n = lg * 4 + r;
                    float v0 = fmaxf(a2[2 * t][r] + xv0, 0.f);
                    float v1 = fmaxf(a2[2 * t + 1][r] + xv1, 0.f);
                    *(uint32*)((char*)z_ent + ((size_t)(s0 + gs) * 2112 + (17 + n) * 64 + e0) * 2) = pkbf(v0, v1);
                }
            }
        }
    }
}

// ---------------------------------------------------------------------------
// k_attnG: full-MFMA attention — ROUND-13 VERSION (reverted; the round-14
// operand-swap variant spilled to scratch: WRITE_SIZE 90 MB, +10 us).
// ---------------------------------------------------------------------------
#define AG_QB   0
#define AG_KB   4224
#define AG_VT   8448
#define AG_PW   12544
#define AG_P32  16640
#define AG_V32  17408
#define AG_MSK  17664
#define AG_TOTAL 17824

__global__ __launch_bounds__(256, 8) void k_attnG(
    const __hip_bfloat16* __restrict__ z_ent,
    const int* __restrict__ mask0, const int* __restrict__ mask1,
    const short* __restrict__ wqkvb, const float* __restrict__ inp_b,
    const short* __restrict__ wos_g, const float* __restrict__ bos_g,
    float* __restrict__ pooled_ws)
{
    extern __shared__ char smem[];
    char*  Qb  = smem + AG_QB;
    char*  Kb  = smem + AG_KB;
    char*  Vt  = smem + AG_VT;
    char*  Pw  = smem + AG_PW;
    float* P32 = (float*)(smem + AG_P32);
    float* V32 = (float*)(smem + AG_V32);
    float* msk = (float*)(smem + AG_MSK);
    char*  ob  = Qb;

    const int tid = threadIdx.x;
    const int s = blockIdx.x;
    const short* zg = (const short*)(z_ent + (size_t)s * 2112);

    if (tid < 16) msk[1 + tid] = (float)mask0[(size_t)s * 16 + tid];
    else if (tid < 32) msk[17 + (tid - 16)] = (float)mask1[(size_t)s * 16 + (tid - 16)];
    else if (tid == 32) msk[0] = 1.0f;

    const int wv = __builtin_amdgcn_readfirstlane(tid >> 6);
    const int l  = tid & 63;
    const int lr = l & 15;
    const int lg = l >> 4;

    // ---- P1: in_proj GEMM (A from global, rows clamped to 32) ----
    {
        short8 bw[3][2]; float bias[3];
        #pragma unroll
        for (int c = 0; c < 3; ++c) {
            int col = (wv * 3 + c) * 16 + lr;
            bw[c][0] = *(const short8*)(wqkvb + col * 64 + lg * 8);
            bw[c][1] = *(const short8*)(wqkvb + col * 64 + 32 + lg * 8);
            bias[c] = inp_b[col];
        }
        for (int rt = 0; rt < 3; ++rt) {
            int arow = rt * 16 + lr;
            if (arow > 32) arow = 32;
            short8 a0 = *(const short8*)(zg + arow * 64 + lg * 8);
            short8 a1 = *(const short8*)(zg + arow * 64 + 32 + lg * 8);
            #pragma unroll
            for (int c = 0; c < 3; ++c) {
                f32x4 acc = {0.f, 0.f, 0.f, 0.f};
                acc = __builtin_amdgcn_mfma_f32_16x16x32_bf16(a0, bw[c][0], acc, 0, 0, 0);
                acc = __builtin_amdgcn_mfma_f32_16x16x32_bf16(a1, bw[c][1], acc, 0, 0, 0);
                int col = (wv * 3 + c) * 16 + lr;
                int rb = rt * 16 + lg * 4;
                #pragma unroll
                for (int r = 0; r < 4; ++r) {
                    int q = rb + r;
                    if (q < 33) {
                        float val = acc[r] + bias[c];
                        if (col < 64) {
                            int h = col >> 4, d = col & 15;
                            *(short*)(Qb + ((h * 33 + q) * 32) + d * 2) = f2bs(val);
                        } else if (col < 128) {
                            int kc = col - 64; int h = kc >> 4, d = kc & 15;
                            *(short*)(Kb + ((h * 33 + q) * 32) + d * 2) = f2bs(val);
                        } else {
                            int vc = col - 128; int h = vc >> 4, d = vc & 15;
                            if (q < 32)
                                *(short*)(Vt + (h * 16 + d) * 64 + ((q * 2) ^ pswz(d))) = f2bs(val);
                            else
                                V32[h * 16 + d] = val;
                        }
                    }
                }
            }
        }
    }
    __syncthreads();

    // ---- P2a: QK MFMA + mask-folded softmax; P packed in regs ----
    uint32 pk[3][4];
    {
        const short8 zero8 = {0, 0, 0, 0, 0, 0, 0, 0};
        short8 kf[3];
        #pragma unroll
        for (int t = 0; t < 3; ++t)
            kf[t] = (lg < 2) ? *(const short8*)(Kb + ((wv * 33 + t * 16 + lr) * 32) + lg * 16) : zero8;
        float mk0 = msk[lr];
        float mk1 = msk[16 + lr];
        float mk2 = (lr == 0) ? msk[32] : 0.f;
        float sc0 = mk0 * 0.25f, bo0 = (mk0 - 1.f) * 40.f;
        float sc1 = mk1 * 0.25f, bo1 = (mk1 - 1.f) * 40.f;
        float sc2 = mk2 * 0.25f, bo2 = (mk2 - 1.f) * 40.f;
        #pragma unroll
        for (int qt = 0; qt < 3; ++qt) {
            short8 qf = (lg < 2) ? *(const short8*)(Qb + ((wv * 33 + qt * 16 + lr) * 32) + lg * 16) : zero8;
            f32x4 z = {0.f, 0.f, 0.f, 0.f};
            f32x4 S0 = __builtin_amdgcn_mfma_f32_16x16x32_bf16(qf, kf[0], z, 0, 0, 0);
            f32x4 S1 = __builtin_amdgcn_mfma_f32_16x16x32_bf16(qf, kf[1], z, 0, 0, 0);
            f32x4 S2 = __builtin_amdgcn_mfma_f32_16x16x32_bf16(qf, kf[2], z, 0, 0, 0);
            #pragma unroll
            for (int r = 0; r < 4; ++r) {
                float e0 = __expf(fmaf(S0[r], sc0, bo0));
                float e1 = __expf(fmaf(S1[r], sc1, bo1));
                float e2 = __expf(fmaf(S2[r], sc2, bo2));
                float sm = e0 + e1 + e2;
                sm += __shfl_xor(sm, 1);
                sm += __shfl_xor(sm, 2);
                sm += __shfl_xor(sm, 4);
                sm += __shfl_xor(sm, 8);
                float inv = 1.0f / sm;
                pk[qt][r] = pkbf(e0 * inv, e1 * inv);
                if (lr == 0) P32[wv * 48 + qt * 16 + lg * 4 + r] = e2 * inv;
            }
        }
    }
    __syncthreads();

    // ---- P2b: PV MFMA via per-wave Pw tile; write ob (aliases Qb) ----
    {
        short8 vf = *(const short8*)(Vt + (wv * 16 + lr) * 64 + ((lg * 16) ^ pswz(lr)));
        float v32reg = V32[wv * 16 + lr];
        f32x4 C[3];
        #pragma unroll
        for (int qt = 0; qt < 3; ++qt) {
            #pragma unroll
            for (int r = 0; r < 4; ++r) {
                int ql = lg * 4 + r;
                uint32 p = pk[qt][r];
                char* prow = Pw + wv * 1024 + ql * 64;
                int sz = pswz(ql);
                *(short*)(prow + ((lr * 2) ^ sz)) = (short)(p & 0xffffu);
                *(short*)(prow + (((16 + lr) * 2) ^ sz)) = (short)(p >> 16);
            }
            short8 pf = *(const short8*)(Pw + wv * 1024 + lr * 64 + ((lg * 16) ^ pswz(lr)));
            f32x4 z = {0.f, 0.f, 0.f, 0.f};
            C[qt] = __builtin_amdgcn_mfma_f32_16x16x32_bf16(pf, vf, z, 0, 0, 0);
        }
        #pragma unroll
        for (int qt = 0; qt < 3; ++qt) {
            #pragma unroll
            for (int r = 0; r < 4; ++r) {
                int q = qt * 16 + lg * 4 + r;
                if (q <= 32) {
                    float cv = C[qt][r] + P32[wv * 48 + q] * v32reg;
                    *(short*)(ob + ((q * 128 + (wv * 16 + lr) * 2) ^ ((q & 7) << 4))) = f2bs(cv);
                }
            }
        }
    }
    __syncthreads();

    // ---- P4: fused (sa@out_proj) GEMM + residual + mask; pooled -> ws ----
    {
        int col = wv * 16 + lr;
        short8 b0 = *(const short8*)(wos_g + col * 64 + lg * 8);
        short8 b1 = *(const short8*)(wos_g + col * 64 + 32 + lg * 8);
        float bias = bos_g[col];
        float ps = 0.f;
        for (int rt = 0; rt < 3; ++rt) {
            int arow = rt * 16 + lr;
            int sw = (arow & 7) << 4;
            short8 a0 = *(const short8*)(ob + ((arow * 128 + lg * 16) ^ sw));
            short8 a1 = *(const short8*)(ob + ((arow * 128 + 64 + lg * 16) ^ sw));
            f32x4 acc = {0.f, 0.f, 0.f, 0.f};
            acc = __builtin_amdgcn_mfma_f32_16x16x32_bf16(a0, b0, acc, 0, 0, 0);
            acc = __builtin_amdgcn_mfma_f32_16x16x32_bf16(a1, b1, acc, 0, 0, 0);
            int rb = rt * 16 + lg * 4;
            #pragma unroll
            for (int r = 0; r < 4; ++r) {
                int row = rb + r;
                if (row < 33) {
                    float zev = bf2f(*(const unsigned short*)(zg + row * 64 + col));
                    ps += msk[row] * (zev + fmaxf(acc[r] + bias, 0.f));
                }
            }
        }
        ps += __shfl_xor(ps, 16); ps += __shfl_xor(ps, 32);
        if (lg == 0) pooled_ws[(size_t)s * 64 + col] = ps * (1.0f / 33.0f);
    }
}

// ---------------------------------------------------------------------------
// k_zinx: fused zin + x-projection (unchanged).
// ---------------------------------------------------------------------------
__global__ __launch_bounds__(256, 2) void k_zinx(
    const float* __restrict__ pooled_ws, const float* __restrict__ zin_x,
    const short* __restrict__ wp2, const float* __restrict__ pool_b,
    const short* __restrict__ wihb, const float* __restrict__ b_ih,
    const float* __restrict__ b_hh, short* __restrict__ xp)
{
    extern __shared__ char smem[];
    char* A1 = smem;
    char* zt = smem + 8192;
    const int tid = threadIdx.x;
    const size_t r0 = (size_t)blockIdx.x * 64;

    for (int i = tid; i < 2048; i += 256) {
        int sl = i >> 5, dp = i & 31;
        float2 v = ((const float2*)(pooled_ws + (r0 + sl) * 64))[dp];
        *(uint32*)(A1 + ((sl * 128 + dp * 4) ^ ((sl & 7) << 4))) = pkbf(v.x, v.y);
    }
    __syncthreads();

    const int wv = __builtin_amdgcn_readfirstlane(tid >> 6);
    const int l = tid & 63;
    const int lr = l & 15;
    const int lg = l >> 4;

    #pragma unroll
    for (int c = 0; c < 2; ++c) {
        int col = (wv * 2 + c) * 16 + lr;
        short8 bf0 = *(const short8*)(wp2 + col * 64 + lg * 8);
        short8 bf1 = *(const short8*)(wp2 + col * 64 + 32 + lg * 8);
        float bias = pool_b[col];
        #pragma unroll
        for (int rt = 0; rt < 4; ++rt) {
            int row16 = rt * 16 + lr;
            short8 a0 = *(const short8*)(A1 + ((row16 * 128 + lg * 16) ^ ((row16 & 7) << 4)));
            short8 a1 = *(const short8*)(A1 + ((row16 * 128 + 64 + lg * 16) ^ ((row16 & 7) << 4)));
            f32x4 acc = {0.f, 0.f, 0.f, 0.f};
            acc = __builtin_amdgcn_mfma_f32_16x16x32_bf16(a0, bf0, acc, 0, 0, 0);
            acc = __builtin_amdgcn_mfma_f32_16x16x32_bf16(a1, bf1, acc, 0, 0, 0);
            #pragma unroll
            for (int r = 0; r < 4; ++r) {
                int row = rt * 16 + lg * 4 + r;
                float v = fmaxf(acc[r] + bias + zin_x[(r0 + row) * 128 + col], 0.f);
                *(short*)(zt + ((row * 256 + col * 2) ^ ((row & 7) << 4))) = f2bs(v);
            }
        }
    }
    __syncthreads();

    short8 af[4][4];
    #pragma unroll
    for (int rt = 0; rt < 4; ++rt)
        #pragma unroll
        for (int kc = 0; kc < 4; ++kc) {
            int row = rt * 16 + lr;
            af[rt][kc] = *(const short8*)(zt + ((row * 256 + kc * 64 + lg * 16) ^ ((row & 7) << 4)));
        }

    for (int ct8 = 0; ct8 < 8; ++ct8) {
        int ct = wv * 8 + ct8;
        int col = ct * 16 + lr;
        short8 bf[4];
        #pragma unroll
        for (int kc = 0; kc < 4; ++kc)
            bf[kc] = *(const short8*)(wihb + (size_t)col * 128 + kc * 32 + lg * 8);
        float bias = b_ih[col] + b_hh[col];
        int g = col >> 7, j = col & 127;
        #pragma unroll
        for (int rt = 0; rt < 4; ++rt) {
            f32x4 acc = {0.f, 0.f, 0.f, 0.f};
            #pragma unroll
            for (int kc = 0; kc < 4; ++kc)
                acc = __builtin_amdgcn_mfma_f32_16x16x32_bf16(af[rt][kc], bf[kc], acc, 0, 0, 0);
            #pragma unroll
            for (int r = 0; r < 4; ++r)
                xp[(r0 + rt * 16 + lg * 4 + r) * 512 + j * 4 + g] = f2bs(acc[r] + bias);
        }
    }
}

// ---------------------------------------------------------------------------
// k_lstm2: MFMA recurrent scan, double-buffered h (kept from round 14).
// ---------------------------------------------------------------------------
__global__ __launch_bounds__(512, 1) void k_lstm2(
    const short* __restrict__ xp, const short* __restrict__ whhb,
    const int* __restrict__ done, float* __restrict__ h_all)
{
    __shared__ short hl[2][16 * 128];
    __shared__ float keepl[64 * 16];
    const int tid = threadIdx.x;
    const int s0 = blockIdx.x * 16;
    const int wv = __builtin_amdgcn_readfirstlane(tid >> 6);
    const int l = tid & 63;
    const int lr = l & 15;
    const int lg = l >> 4;

    for (int i = tid; i < 1024; i += 512) {
        int t = i >> 4, ls = i & 15;
        keepl[i] = done[t * 32 + ((s0 + ls) >> 3)] ? 0.f : 1.f;
    }
    for (int i = tid; i < 1024; i += 512) ((uint32*)hl[0])[i] = 0;

    short8 bf[4][4];
    #pragma unroll
    for (int gi = 0; gi < 4; ++gi) {
        int col = (gi * 8 + wv) * 16 + lr;
        #pragma unroll
        for (int kc = 0; kc < 4; ++kc)
            bf[gi][kc] = *(const short8*)(whhb + (size_t)col * 128 + kc * 32 + lg * 8);
    }
    float c0 = 0.f, c1 = 0.f, c2 = 0.f, c3 = 0.f;
    const int jcol = wv * 16 + lr;

    short4 xn[4];
    #pragma unroll
    for (int r = 0; r < 4; ++r)
        xn[r] = *(const short4*)(xp + ((size_t)(s0 + lg * 4 + r)) * 512 + jcol * 4);
    __syncthreads();

    for (int t = 0; t < T_DIM; ++t) {
        char* hr = (char*)hl[t & 1];
        char* hw = (char*)hl[(t + 1) & 1];
        short4 xc[4];
        #pragma unroll
        for (int r = 0; r < 4; ++r) xc[r] = xn[r];
        if (t < 63) {
            #pragma unroll
            for (int r = 0; r < 4; ++r)
                xn[r] = *(const short4*)(xp + ((size_t)(t + 1) * 256 + s0 + lg * 4 + r) * 512 + jcol * 4);
        }
        short8 af[4];
        #pragma unroll
        for (int kc = 0; kc < 4; ++kc)
            af[kc] = *(const short8*)(hr + ((lr * 256 + kc * 64 + lg * 16) ^ ((lr & 7) << 4)));
        f32x4 z = {0.f, 0.f, 0.f, 0.f};
        f32x4 Ci = z, Cf = z, Cg = z, Co = z;
        #pragma unroll
        for (int kc = 0; kc < 4; ++kc) {
            Ci = __builtin_amdgcn_mfma_f32_16x16x32_bf16(af[kc], bf[0][kc], Ci, 0, 0, 0);
            Cf = __builtin_amdgcn_mfma_f32_16x16x32_bf16(af[kc], bf[1][kc], Cf, 0, 0, 0);
            Cg = __builtin_amdgcn_mfma_f32_16x16x32_bf16(af[kc], bf[2][kc], Cg, 0, 0, 0);
            Co = __builtin_amdgcn_mfma_f32_16x16x32_bf16(af[kc], bf[3][kc], Co, 0, 0, 0);
        }

        #pragma unroll
        for (int r = 0; r < 4; ++r) {
            int sl = lg * 4 + r;
            float kt = keepl[t * 16 + sl];
            float gi = bf2f((unsigned short)xc[r].x) + Ci[r];
            float gf = bf2f((unsigned short)xc[r].y) + Cf[r];
            float gg = bf2f((unsigned short)xc[r].z) + Cg[r];
            float go = bf2f((unsigned short)xc[r].w) + Co[r];
            float cc = (r == 0 ? c0 : r == 1 ? c1 : r == 2 ? c2 : c3) * kt;
            cc = sigf(gf) * cc + sigf(gi) * tanhf(gg);
            float hn = sigf(go) * tanhf(cc);
            if (r == 0) c0 = cc; else if (r == 1) c1 = cc; else if (r == 2) c2 = cc; else c3 = cc;
            float kn = (t < 63) ? keepl[(t + 1) * 16 + sl] : 1.f;
            *(short*)(hw + ((sl * 256 + jcol * 2) ^ ((sl & 7) << 4))) = f2bs(hn * kn);
            h_all[((size_t)t * 256 + s0 + sl) * 128 + jcol] = hn;
        }
        __syncthreads();
    }
}

// ---------------------------------------------------------------------------
// Kernel: categorical heads (unchanged)
// ---------------------------------------------------------------------------
__global__ __launch_bounds__(256) void k_heads(
    const float* __restrict__ h_all, const int* __restrict__ actions,
    const float* __restrict__ h0w, const float* __restrict__ h0b,
    const float* __restrict__ h1w, const float* __restrict__ h1b,
    float* __restrict__ out)
{
    __shared__ float w0[640], w1[640], b0[8], b1[8];
    const int tid = threadIdx.x;
    for (int i = tid; i < 640; i += 256) { w0[i] = h0w[i]; w1[i] = h1w[i]; }
    if (tid < 5) { b0[tid] = h0b[tid]; b1[tid] = h1b[tid]; }
    __syncthreads();
    const int g = blockIdx.x * 256 + tid;
    const float* h = h_all + (size_t)g * 128;
    float l0[5], l1[5];
    #pragma unroll
    for (int cc = 0; cc < 5; ++cc) { l0[cc] = b0[cc]; l1[cc] = b1[cc]; }
    for (int j = 0; j < 128; ++j) {
        float hv = h[j];
        #pragma unroll
        for (int cc = 0; cc < 5; ++cc) {
            l0[cc] = fmaf(w0[cc * 128 + j], hv, l0[cc]);
            l1[cc] = fmaf(w1[cc * 128 + j], hv, l1[cc]);
        }
    }
    int a0 = actions[(size_t)g * 2], a1 = actions[(size_t)g * 2 + 1];
    float m0 = l0[0], m1 = l1[0];
    #pragma unroll
    for (int cc = 1; cc < 5; ++cc) { m0 = fmaxf(m0, l0[cc]); m1 = fmaxf(m1, l1[cc]); }
    float s0 = 0.f, s1 = 0.f;
    #pragma unroll
    for (int cc = 0; cc < 5; ++cc) { s0 += expf(l0[cc] - m0); s1 += expf(l1[cc] - m1); }
    float lse0 = m0 + logf(s0), lse1 = m1 + logf(s1);
    float ent0 = 0.f, ent1 = 0.f, lp0 = 0.f, lp1 = 0.f;
    #pragma unroll
    for (int cc = 0; cc < 5; ++cc) {
        float p0 = l0[cc] - lse0, p1 = l1[cc] - lse1;
        ent0 -= expf(p0) * p0;
        ent1 -= expf(p1) * p1;
        if (cc == a0) lp0 = p0;
        if (cc == a1) lp1 = p1;
    }
    out[ACT_OFF + (size_t)g * 2]     = (float)a0;
    out[ACT_OFF + (size_t)g * 2 + 1] = (float)a1;
    out[LP_OFF + g]                  = lp0 * lp1;
    out[ENT_OFF + (size_t)g * 2]     = ent0;
    out[ENT_OFF + (size_t)g * 2 + 1] = ent1;
}

extern "C" void kernel_launch(void* const* d_in, const int* in_sizes, int n_in,
                              void* d_out, int out_size, void* d_ws, size_t ws_size,
                              hipStream_t stream)
{
    const float* x_agent = (const float*)d_in[0];
    const float* x_lidar = (const float*)d_in[1];
    const float* x_safe  = (const float*)d_in[2];
    const float* x_ent0  = (const float*)d_in[3];
    const float* x_ent1  = (const float*)d_in[4];
    const int*   mask0   = (const int*)d_in[5];
    const int*   mask1   = (const int*)d_in[6];
    const int*   done    = (const int*)d_in[7];
    const int*   actions = (const int*)d_in[8];
    const float* conv_w  = (const float*)d_in[9];
    const float* conv_b  = (const float*)d_in[10];
    const float* self_w  = (const float*)d_in[11];
    const float* self_b  = (const float*)d_in[12];
    const float* ent0_w  = (const float*)d_in[13];
    const float* ent0_b  = (const float*)d_in[14];
    const float* ent1_w  = (const float*)d_in[15];
    const float* ent1_b  = (const float*)d_in[16];
    const float* inp_w   = (const float*)d_in[17];
    const float* inp_b   = (const float*)d_in[18];
    const float* outp_w  = (const float*)d_in[19];
    const float* outp_b  = (const float*)d_in[20];
    const float* sa_w    = (const float*)d_in[21];
    const float* sa_b    = (const float*)d_in[22];
    const float* pool_w  = (const float*)d_in[23];
    const float* pool_b  = (const float*)d_in[24];
    const float* w_ih    = (const float*)d_in[25];
    const float* w_hh    = (const float*)d_in[26];
    const float* b_ih    = (const float*)d_in[27];
    const float* b_hh    = (const float*)d_in[28];
    const float* h0w     = (const float*)d_in[29];
    const float* h0b     = (const float*)d_in[30];
    const float* h1w     = (const float*)d_in[31];
    const float* h1b     = (const float*)d_in[32];

    // ws layout
    __hip_bfloat16* z_ent = (__hip_bfloat16*)d_ws;
    float* zin_x  = (float*)((char*)d_ws + (size_t)S_TOT * 2112 * 2);
    float* pooled = zin_x + (size_t)S_TOT * 128;
    float* h_all  = pooled + (size_t)S_TOT * 64;
    short* xp     = (short*)(h_all + (size_t)S_TOT * 128);
    short* wqkvb  = xp + (size_t)S_TOT * 512;
    short* Wf     = wqkvb + 12288;
    short* We0    = Wf + 102400;
    short* We1    = We0 + 1024;
    short* wos    = We1 + 1024;
    float* bos    = (float*)(wos + 4096);
    short* wihb   = (short*)(bos + 64);
    short* whhb   = wihb + 65536;
    short* wp2    = whhb + 65536;

    k_cvt2<<<400, 256, 0, stream>>>(inp_w, outp_w, outp_b, sa_w, sa_b, self_w, pool_w,
                                    ent0_w, ent1_w, w_ih, w_hh,
                                    wqkvb, Wf, We0, We1, wos, bos, wihb, whhb, wp2);

    k_frontN<<<S_TOT / FN_SB, 256, FN_TOTAL, stream>>>(
        x_agent, x_lidar, x_safe, x_ent0, x_ent1,
        conv_w, conv_b, self_b, ent0_b, ent1_b,
        Wf, We0, We1, z_ent, zin_x);

    k_attnG<<<S_TOT, 256, AG_TOTAL, stream>>>(
        z_ent, mask0, mask1, wqkvb, inp_b, wos, bos, pooled);

    k_zinx<<<256, 256, 24576, stream>>>(pooled, zin_x, wp2, pool_b, wihb, b_ih, b_hh, xp);

    k_lstm2<<<16, 512, 0, stream>>>(xp, whhb, done, h_all);

    k_heads<<<S_TOT / 256, 256, 0, stream>>>(h_all, actions, h0w, h0b, h1w, h1b, (float*)d_out);
}